// Round 1
// baseline (302.207 us; speedup 1.0000x reference)
//
#include <hip/hip_runtime.h>
#include <stdint.h>

#define D_ 256
#define NQ_ 512
#define NK_ 512
#define NP_ (NQ_*NK_)

typedef __attribute__((ext_vector_type(8))) __bf16 bf16x8;
typedef __attribute__((ext_vector_type(4))) float f32x4;

__device__ __forceinline__ unsigned short f2bf(float f) {
  unsigned u = __builtin_bit_cast(unsigned, f);
  u += 0x7FFFu + ((u >> 16) & 1u);   // RNE
  return (unsigned short)(u >> 16);
}
__device__ __forceinline__ unsigned encf(float f) {  // order-preserving float->uint
  unsigned u = __builtin_bit_cast(unsigned, f);
  return (u & 0x80000000u) ? ~u : (u | 0x80000000u);
}
__device__ __forceinline__ float decf(unsigned e) {
  unsigned u = (e & 0x80000000u) ? (e ^ 0x80000000u) : ~e;
  return __builtin_bit_cast(float, u);
}

// ---------------- K0: mask dtype sniff + min-slot init ----------------
__global__ void kinit(const unsigned* __restrict__ maskw,
                      unsigned* __restrict__ wsMin, unsigned* __restrict__ wsFlag) {
  int l = threadIdx.x;  // 64
  unsigned a01 = 1, af = 1;
  for (int i = 0; i < 4; ++i) {
    unsigned v = maskw[l*4 + i];
    a01 &= (v == 0u || v == 1u) ? 1u : 0u;
    af  &= (v == 0u || v == 0x3f800000u) ? 1u : 0u;
  }
  unsigned long long b01 = __ballot(a01 != 0), bf = __ballot(af != 0);
  if (l == 0) {
    *wsFlag = (b01 == ~0ull) ? 1u : ((bf == ~0ull) ? 2u : 0u); // 1=int32, 2=f32, 0=byte
    *wsMin = 0xFFFFFFFFu;
  }
}

// ---------------- Kc: C = aW1[:,512:768] -> bf16 [e][256] ----------------
__global__ __launch_bounds__(256) void kconv(const float* __restrict__ aW1,
                                             unsigned short* __restrict__ Cb) {
  int tid = blockIdx.x * 256 + threadIdx.x;   // 64 blocks
  int base = tid * 4;
  int e = base >> 8, c = base & 255;
  const float4 v = *(const float4*)(aW1 + e*768 + 512 + c);
  ushort4 o;
  o.x = f2bf(v.x); o.y = f2bf(v.y); o.z = f2bf(v.z); o.w = f2bf(v.w);
  *(ushort4*)(Cb + base) = o;
}

// ---------------- K1: U'[q][e] = A.x + ab1 ; V[e][k] = B.s ----------------
__global__ __launch_bounds__(256) void kprep(const float* __restrict__ x,
                                             const float* __restrict__ source,
                                             const float* __restrict__ aW1,
                                             const float* __restrict__ ab1,
                                             float* __restrict__ Up, float* __restrict__ Vm) {
  __shared__ float xs[256], ss[256];
  int t = threadIdx.x, w = t >> 6, l = t & 63;
  int b = blockIdx.x;            // q for U, k for V
  xs[t] = x[t*512 + b];
  ss[t] = source[t*512 + b];
  __syncthreads();
  for (int i = 0; i < 64; ++i) {
    int e = w + 4*i;
    const float* wr = aW1 + e*768;
    float su = 0.f, sv = 0.f;
    #pragma unroll
    for (int jj = 0; jj < 4; ++jj) {
      su += wr[l + 64*jj]       * xs[l + 64*jj];
      sv += wr[256 + l + 64*jj] * ss[l + 64*jj];
    }
    #pragma unroll
    for (int off = 32; off; off >>= 1) {
      su += __shfl_xor(su, off);
      sv += __shfl_xor(sv, off);
    }
    if (l == 0) { Up[b*256 + e] = su + ab1[e]; Vm[e*512 + b] = sv; }
  }
}

// ---------------- KB: fused scores GEMM (T = C@dist, epilogue relu-dot) ----------------
// block: 256 thr (4 waves over M=256), tile M=256 x N=64 pairs, K=256 in 8 steps of 32
__global__ __launch_bounds__(256) void kscores(
    const float* __restrict__ dist, const unsigned short* __restrict__ Cb,
    const float* __restrict__ Up, const float* __restrict__ Vm,
    const float* __restrict__ aW2, const float* __restrict__ ab2,
    float* __restrict__ outScores, unsigned* __restrict__ wsMin) {
  __shared__ __align__(16) unsigned char ldsA[256*64]; // [e][32k] bf16, chunk-XOR key=(e>>1)&3
  __shared__ __align__(16) unsigned char ldsB[64*64];  // [j][32k] bf16, chunk-XOR key=(j>>1)&3
  __shared__ float u_s[256], aw2_s[256];
  __shared__ float red[4][64];

  const int t = threadIdx.x;
  const int w = t >> 6;
  const int l = t & 63;
  const int l15 = l & 15;
  const int g = l >> 4;

  const int p0 = blockIdx.x * 64;
  const int q  = p0 >> 9;
  const int k0 = p0 & 511;

  u_s[t]   = Up[q*256 + t];
  aw2_s[t] = aW2[t];

  f32x4 acc[4][4];
  #pragma unroll
  for (int m = 0; m < 4; ++m)
    #pragma unroll
    for (int n = 0; n < 4; ++n) acc[m][n] = (f32x4){0.f, 0.f, 0.f, 0.f};

  const int keyoff = ((g ^ ((l15 >> 1) & 3)) << 4); // frag-read chunk byte offset
  const int quad1 = (w + g) & 3;                    // lane-group-rotated c-quads
  const int quad2 = quad1 + 4;

  for (int kk = 0; kk < 8; ++kk) {
    __syncthreads();
    // ---- stage A (Cb -> LDS), linear writes, XOR on source chunk
    #pragma unroll
    for (int i = 0; i < 4; ++i) {
      int m = t + 256*i;                 // chunk 0..1023 ; addr = m*16
      int e = m >> 2, pc = m & 3;
      int cc = pc ^ ((e >> 1) & 3);
      *(uint4*)(ldsA + m*16) = *(const uint4*)(Cb + e*256 + kk*32 + cc*8);
    }
    // ---- stage B (dist fp32 -> bf16 -> LDS [j][k]); row j = l
    {
      size_t base = (size_t)(kk*32) * NP_ + (size_t)(p0 + l);
      float v0[4], v1[4];
      #pragma unroll
      for (int i = 0; i < 4; ++i) v0[i] = dist[base + (size_t)(quad1*4 + i) * NP_];
      #pragma unroll
      for (int i = 0; i < 4; ++i) v1[i] = dist[base + (size_t)(quad2*4 + i) * NP_];
      {
        unsigned lo = (unsigned)f2bf(v0[0]) | ((unsigned)f2bf(v0[1]) << 16);
        unsigned hi = (unsigned)f2bf(v0[2]) | ((unsigned)f2bf(v0[3]) << 16);
        int c0 = quad1*4, cc = c0 >> 3, h = (c0 >> 2) & 1;
        int pcw = cc ^ ((l >> 1) & 3);
        *(uint2*)(ldsB + l*64 + pcw*16 + h*8) = make_uint2(lo, hi);
      }
      {
        unsigned lo = (unsigned)f2bf(v1[0]) | ((unsigned)f2bf(v1[1]) << 16);
        unsigned hi = (unsigned)f2bf(v1[2]) | ((unsigned)f2bf(v1[3]) << 16);
        int c0 = quad2*4, cc = c0 >> 3, h = (c0 >> 2) & 1;
        int pcw = cc ^ ((l >> 1) & 3);
        *(uint2*)(ldsB + l*64 + pcw*16 + h*8) = make_uint2(lo, hi);
      }
    }
    __syncthreads();
    // ---- compute
    bf16x8 a[4], b[4];
    #pragma unroll
    for (int m = 0; m < 4; ++m) {
      int e = w*64 + m*16 + l15;
      a[m] = *(const bf16x8*)(ldsA + e*64 + keyoff);
    }
    #pragma unroll
    for (int n = 0; n < 4; ++n) {
      int j = n*16 + l15;
      b[n] = *(const bf16x8*)(ldsB + j*64 + keyoff);
    }
    #pragma unroll
    for (int m = 0; m < 4; ++m)
      #pragma unroll
      for (int n = 0; n < 4; ++n)
        acc[m][n] = __builtin_amdgcn_mfma_f32_16x16x32_bf16(a[m], b[n], acc[m][n], 0, 0, 0);
  }
  __syncthreads();

  // ---- epilogue: score[j] = ab2 + sum_e aW2[e]*relu(T + U' + V)
  float part[4];
  #pragma unroll
  for (int n = 0; n < 4; ++n) {
    int j = k0 + n*16 + l15;
    float s = 0.f;
    #pragma unroll
    for (int m = 0; m < 4; ++m) {
      #pragma unroll
      for (int r = 0; r < 4; ++r) {
        int e = w*64 + m*16 + g*4 + r;
        float gv = acc[m][n][r] + u_s[e] + Vm[e*512 + j];
        s += aw2_s[e] * fmaxf(gv, 0.f);
      }
    }
    s += __shfl_xor(s, 16);
    s += __shfl_xor(s, 32);
    part[n] = s;
  }
  if (l < 16) {
    #pragma unroll
    for (int n = 0; n < 4; ++n) red[w][n*16 + l] = part[n];
  }
  __syncthreads();
  if (t < 64) {
    float s = red[0][t] + red[1][t] + red[2][t] + red[3][t] + ab2[0];
    outScores[p0 + t] = s;
    float mn = s;
    #pragma unroll
    for (int off = 32; off; off >>= 1) mn = fminf(mn, __shfl_xor(mn, off));
    if (t == 0) atomicMin(wsMin, encf(mn));
  }
}

// ---------------- KM: mask + softmax + message + merge MLP (one block per q) ----------------
__global__ __launch_bounds__(256) void kmerge(
    const float* __restrict__ x, const float* __restrict__ source,
    const void* __restrict__ maskp,
    const float* __restrict__ mW1, const float* __restrict__ mb1,
    const float* __restrict__ mW2, const float* __restrict__ mb2,
    const unsigned* __restrict__ wsMin, const unsigned* __restrict__ wsFlag,
    float* __restrict__ outMain, float* __restrict__ scores) {
  __shared__ float srow[512];
  __shared__ float cat_s[512];
  __shared__ float h2_s[512];
  __shared__ float redl[8];
  const int t = threadIdx.x, w = t >> 6, l = t & 63;
  const int q = blockIdx.x;
  const float neg = decf(*wsMin) - 20.0f;
  const unsigned flag = *wsFlag;

  // mask, write masked scores back (these are output 1)
  for (int k = t; k < 512; k += 256) {
    float raw = scores[q*512 + k];
    bool mv;
    if (flag == 1)      mv = ((const int*)maskp)[q*512 + k] != 0;
    else if (flag == 2) mv = ((const float*)maskp)[q*512 + k] != 0.f;
    else                mv = ((const unsigned char*)maskp)[q*512 + k] != 0;
    float ms = raw + (mv ? 0.f : neg);
    scores[q*512 + k] = ms;
    srow[k] = ms;
  }
  __syncthreads();
  // row max
  float lm = fmaxf(srow[t], srow[t + 256]);
  #pragma unroll
  for (int off = 32; off; off >>= 1) lm = fmaxf(lm, __shfl_xor(lm, off));
  if (l == 0) redl[w] = lm;
  __syncthreads();
  float rmax = fmaxf(fmaxf(redl[0], redl[1]), fmaxf(redl[2], redl[3]));
  // exp + sum
  float e0 = __expf(srow[t] - rmax), e1 = __expf(srow[t + 256] - rmax);
  srow[t] = e0; srow[t + 256] = e1;
  float ls = e0 + e1;
  #pragma unroll
  for (int off = 32; off; off >>= 1) ls += __shfl_xor(ls, off);
  if (l == 0) redl[4 + w] = ls;
  __syncthreads();
  float inv = 1.0f / (redl[4] + redl[5] + redl[6] + redl[7]);
  srow[t] *= inv; srow[t + 256] *= inv;
  cat_s[t] = x[t*512 + q];
  __syncthreads();
  // message[d] = sum_k prob[k]*source[d][k]  (wave-per-d)
  for (int i = 0; i < 64; ++i) {
    int d = w + 4*i;
    const float* sr = source + d*512;
    float s = 0.f;
    #pragma unroll
    for (int jj = 0; jj < 8; ++jj) s += srow[l + 64*jj] * sr[l + 64*jj];
    #pragma unroll
    for (int off = 32; off; off >>= 1) s += __shfl_xor(s, off);
    if (l == 0) cat_s[256 + d] = s;
  }
  __syncthreads();
  // h2 = relu(mW1 @ cat + mb1)
  for (int i = 0; i < 128; ++i) {
    int o = w + 4*i;
    const float* wr = mW1 + o*512;
    float s = 0.f;
    #pragma unroll
    for (int jj = 0; jj < 8; ++jj) s += wr[l + 64*jj] * cat_s[l + 64*jj];
    #pragma unroll
    for (int off = 32; off; off >>= 1) s += __shfl_xor(s, off);
    if (l == 0) h2_s[o] = fmaxf(s + mb1[o], 0.f);
  }
  __syncthreads();
  // out = mW2 @ h2 + mb2
  for (int i = 0; i < 64; ++i) {
    int o = w + 4*i;
    const float* wr = mW2 + o*512;
    float s = 0.f;
    #pragma unroll
    for (int jj = 0; jj < 8; ++jj) s += wr[l + 64*jj] * h2_s[l + 64*jj];
    #pragma unroll
    for (int off = 32; off; off >>= 1) s += __shfl_xor(s, off);
    if (l == 0) outMain[o*512 + q] = s + mb2[o];
  }
}

extern "C" void kernel_launch(void* const* d_in, const int* in_sizes, int n_in,
                              void* d_out, int out_size, void* d_ws, size_t ws_size,
                              hipStream_t stream) {
  const float* x      = (const float*)d_in[0];
  const float* source = (const float*)d_in[1];
  const float* dist   = (const float*)d_in[2];
  const void*  mask   = (const void*)d_in[3];
  const float* aW1    = (const float*)d_in[4];
  const float* ab1    = (const float*)d_in[5];
  const float* aW2    = (const float*)d_in[6];
  const float* ab2    = (const float*)d_in[7];
  const float* mW1    = (const float*)d_in[8];
  const float* mb1    = (const float*)d_in[9];
  const float* mW2    = (const float*)d_in[10];
  const float* mb2    = (const float*)d_in[11];

  float* outMain = (float*)d_out;             // (1,256,512) -> 131072 floats
  float* scores  = outMain + 256*512;         // (1,512,512) -> 262144 floats

  char* ws = (char*)d_ws;
  unsigned* wsMin  = (unsigned*)ws;           // [0,4)
  unsigned* wsFlag = wsMin + 1;               // [4,8)
  unsigned short* Cb = (unsigned short*)(ws + 1024);       // 131072 B
  float* Up = (float*)(ws + 132096);                       // 512*256*4 = 524288 B
  float* Vm = (float*)(ws + 656384);                       // 256*512*4 = 524288 B

  hipLaunchKernelGGL(kinit,  dim3(1),    dim3(64),  0, stream,
                     (const unsigned*)mask, wsMin, wsFlag);
  hipLaunchKernelGGL(kconv,  dim3(64),   dim3(256), 0, stream, aW1, Cb);
  hipLaunchKernelGGL(kprep,  dim3(512),  dim3(256), 0, stream, x, source, aW1, ab1, Up, Vm);
  hipLaunchKernelGGL(kscores,dim3(4096), dim3(256), 0, stream,
                     dist, Cb, Up, Vm, aW2, ab2, scores, wsMin);
  hipLaunchKernelGGL(kmerge, dim3(512),  dim3(256), 0, stream,
                     x, source, mask, mW1, mb1, mW2, mb2, wsMin, wsFlag, outMain, scores);
}

// Round 2
// 206.105 us; speedup vs baseline: 1.4663x; 1.4663x over previous
//
#include <hip/hip_runtime.h>
#include <stdint.h>

#define D_ 256
#define NQ_ 512
#define NK_ 512
#define NP_ (NQ_*NK_)

typedef __attribute__((ext_vector_type(8))) __bf16 bf16x8;
typedef __attribute__((ext_vector_type(4))) float f32x4;

__device__ __forceinline__ unsigned short f2bf(float f) {
  unsigned u = __builtin_bit_cast(unsigned, f);
  u += 0x7FFFu + ((u >> 16) & 1u);   // RNE
  return (unsigned short)(u >> 16);
}
__device__ __forceinline__ unsigned encf(float f) {  // order-preserving float->uint
  unsigned u = __builtin_bit_cast(unsigned, f);
  return (u & 0x80000000u) ? ~u : (u | 0x80000000u);
}
__device__ __forceinline__ float decf(unsigned e) {
  unsigned u = (e & 0x80000000u) ? (e ^ 0x80000000u) : ~e;
  return __builtin_bit_cast(float, u);
}

// ---------------- K0: mask dtype sniff + min-slot init ----------------
__global__ void kinit(const unsigned* __restrict__ maskw,
                      unsigned* __restrict__ wsMin, unsigned* __restrict__ wsFlag) {
  int l = threadIdx.x;  // 64
  unsigned a01 = 1, af = 1;
  for (int i = 0; i < 4; ++i) {
    unsigned v = maskw[l*4 + i];
    a01 &= (v == 0u || v == 1u) ? 1u : 0u;
    af  &= (v == 0u || v == 0x3f800000u) ? 1u : 0u;
  }
  unsigned long long b01 = __ballot(a01 != 0), bf = __ballot(af != 0);
  if (l == 0) {
    *wsFlag = (b01 == ~0ull) ? 1u : ((bf == ~0ull) ? 2u : 0u); // 1=int32, 2=f32, 0=byte
    *wsMin = 0xFFFFFFFFu;
  }
}

// ---------------- Kc: all bf16 operand conversions ----------------
// regions (blocks): [0,64) Cb=aW1[:,512:768]; [64,192) source_bf16; [192,448) mW1b;
// [448,576) mW2b; [576,640) aW1A; [640,704) aW1B; [704,1216) xT->catT[:, :256];
// [1216,1728) sourceT
__global__ __launch_bounds__(256) void kconvert(
    const float* __restrict__ aW1, const float* __restrict__ source,
    const float* __restrict__ x, const float* __restrict__ mW1,
    const float* __restrict__ mW2,
    unsigned short* __restrict__ Cb, unsigned short* __restrict__ srcbf,
    unsigned short* __restrict__ srcT, unsigned short* __restrict__ mW1b,
    unsigned short* __restrict__ mW2b, unsigned short* __restrict__ aW1A,
    unsigned short* __restrict__ aW1B, unsigned short* __restrict__ catT) {
  const int b = blockIdx.x, t = threadIdx.x;
  if (b < 704) {
    const float* src; unsigned short* dst;
    if (b < 64)        { int j = b*1024 + t*4;       int e=j>>8, c=j&255; src = aW1 + e*768 + 512 + c; dst = Cb + j; }
    else if (b < 192)  { int j = (b-64)*1024 + t*4;  src = source + j;    dst = srcbf + j; }
    else if (b < 448)  { int j = (b-192)*1024 + t*4; src = mW1 + j;       dst = mW1b + j; }
    else if (b < 576)  { int j = (b-448)*1024 + t*4; src = mW2 + j;       dst = mW2b + j; }
    else if (b < 640)  { int j = (b-576)*1024 + t*4; int e=j>>8, c=j&255; src = aW1 + e*768 + c;       dst = aW1A + j; }
    else               { int j = (b-640)*1024 + t*4; int e=j>>8, c=j&255; src = aW1 + e*768 + 256 + c; dst = aW1B + j; }
    const float4 v = *(const float4*)src;
    ushort4 o; o.x=f2bf(v.x); o.y=f2bf(v.y); o.z=f2bf(v.z); o.w=f2bf(v.w);
    *(ushort4*)dst = o;
  } else if (b < 1216) {
    int qq = b - 704;
    catT[qq*512 + t] = f2bf(x[(size_t)t*512 + qq]);
  } else {
    int kk = b - 1216;
    srcT[kk*256 + t] = f2bf(source[(size_t)t*512 + kk]);
  }
}

// ---------------- direct-from-global MFMA GEMM ----------------
// D[m][n] = sum_k A[m][k]*B[n][k] (+bias) ; A [M][lda], B [N][ldb] bf16 row-major-in-k
// EPI bits: 1=bf16-out, 2=relu, 4=bias[col], 8=bias[row]
template<int EPI, int KTILES>
__global__ __launch_bounds__(256) void gemm_k(
    const unsigned short* __restrict__ A, int lda,
    const unsigned short* __restrict__ B, int ldb,
    const float* __restrict__ bias,
    void* __restrict__ Dst, int ldd, int nTilesN) {
  const int t = threadIdx.x, w = t >> 6, l = t & 63, l15 = l & 15, g = l >> 4;
  const int bm = blockIdx.x / nTilesN, bn = blockIdx.x % nTilesN;
  const int m0 = bm*64 + w*16, n0 = bn*64;
  const unsigned short* Ap = A + (size_t)(m0 + l15)*lda + g*8;
  const unsigned short* Bp = B + (size_t)(n0 + l15)*ldb + g*8;
  f32x4 acc[4];
  #pragma unroll
  for (int n = 0; n < 4; ++n) acc[n] = (f32x4){0.f,0.f,0.f,0.f};
  #pragma unroll 2
  for (int kk = 0; kk < KTILES; ++kk) {
    bf16x8 a = *(const bf16x8*)(Ap + kk*32);
    #pragma unroll
    for (int n = 0; n < 4; ++n) {
      bf16x8 b = *(const bf16x8*)(Bp + (size_t)n*16*ldb + kk*32);
      acc[n] = __builtin_amdgcn_mfma_f32_16x16x32_bf16(a, b, acc[n], 0, 0, 0);
    }
  }
  #pragma unroll
  for (int n = 0; n < 4; ++n) {
    const int col = n0 + n*16 + l15;
    const float bc = (EPI & 4) ? bias[col] : 0.f;
    #pragma unroll
    for (int r = 0; r < 4; ++r) {
      const int m = m0 + g*4 + r;
      float v = acc[n][r] + bc;
      if (EPI & 8) v += bias[m];
      if (EPI & 2) v = fmaxf(v, 0.f);
      if (EPI & 1) ((unsigned short*)Dst)[(size_t)m*ldd + col] = f2bf(v);
      else         ((float*)Dst)[(size_t)m*ldd + col] = v;
    }
  }
}

// ---------------- KB: fused scores GEMM (A direct from L2, B dbuf+prefetch) ----------------
__global__ __launch_bounds__(256) void kscores(
    const float* __restrict__ dist, const unsigned short* __restrict__ Cb,
    const float* __restrict__ Up, const float* __restrict__ Vm,
    const float* __restrict__ aW2, const float* __restrict__ ab2,
    float* __restrict__ outScores, unsigned* __restrict__ wsMin) {
  __shared__ __align__(16) unsigned char ldsB[2][64*64]; // [j][32k] bf16, chunk-XOR key=(j>>1)&3
  __shared__ float u_s[256], aw2_s[256];
  __shared__ float red[4][64];

  const int t = threadIdx.x;
  const int w = t >> 6;
  const int l = t & 63;
  const int l15 = l & 15;
  const int g = l >> 4;

  const int p0 = blockIdx.x * 64;
  const int q  = p0 >> 9;
  const int k0 = p0 & 511;

  u_s[t]   = Up[q*256 + t];
  aw2_s[t] = aW2[t];

  f32x4 acc[4][4];
  #pragma unroll
  for (int m = 0; m < 4; ++m)
    #pragma unroll
    for (int n = 0; n < 4; ++n) acc[m][n] = (f32x4){0.f, 0.f, 0.f, 0.f};

  const int keyoff = ((g ^ ((l15 >> 1) & 3)) << 4);
  const int quad1 = (w + g) & 3;
  const int quad2 = quad1 + 4;
  const int wr1 = l*64 + (((quad1 >> 1) ^ ((l >> 1) & 3)) << 4) + ((quad1 & 1) << 3);
  const int wr2 = l*64 + (((quad2 >> 1) ^ ((l >> 1) & 3)) << 4) + ((quad2 & 1) << 3);

  // prefetch kk=0
  float v0[4], v1[4];
  #pragma unroll
  for (int i = 0; i < 4; ++i) v0[i] = dist[(size_t)(quad1*4 + i)*NP_ + p0 + l];
  #pragma unroll
  for (int i = 0; i < 4; ++i) v1[i] = dist[(size_t)(quad2*4 + i)*NP_ + p0 + l];

  int buf = 0;
  for (int kk = 0; kk < 8; ++kk) {
    *(uint2*)(&ldsB[buf][wr1]) = make_uint2(
        (unsigned)f2bf(v0[0]) | ((unsigned)f2bf(v0[1]) << 16),
        (unsigned)f2bf(v0[2]) | ((unsigned)f2bf(v0[3]) << 16));
    *(uint2*)(&ldsB[buf][wr2]) = make_uint2(
        (unsigned)f2bf(v1[0]) | ((unsigned)f2bf(v1[1]) << 16),
        (unsigned)f2bf(v1[2]) | ((unsigned)f2bf(v1[3]) << 16));
    if (kk < 7) {
      size_t base = (size_t)((kk + 1) * 32) * NP_ + (size_t)(p0 + l);
      #pragma unroll
      for (int i = 0; i < 4; ++i) v0[i] = dist[base + (size_t)(quad1*4 + i) * NP_];
      #pragma unroll
      for (int i = 0; i < 4; ++i) v1[i] = dist[base + (size_t)(quad2*4 + i) * NP_];
    }
    __syncthreads();
    bf16x8 a[4], b[4];
    #pragma unroll
    for (int m = 0; m < 4; ++m)
      a[m] = *(const bf16x8*)(Cb + (size_t)(w*64 + m*16 + l15)*256 + kk*32 + g*8);
    #pragma unroll
    for (int n = 0; n < 4; ++n)
      b[n] = *(const bf16x8*)(&ldsB[buf][(n*16 + l15)*64 + keyoff]);
    #pragma unroll
    for (int m = 0; m < 4; ++m)
      #pragma unroll
      for (int n = 0; n < 4; ++n)
        acc[m][n] = __builtin_amdgcn_mfma_f32_16x16x32_bf16(a[m], b[n], acc[m][n], 0, 0, 0);
    buf ^= 1;
  }
  __syncthreads();

  // epilogue: score[j] = ab2 + sum_e aW2[e]*relu(T + U' + V)
  float part[4];
  #pragma unroll
  for (int n = 0; n < 4; ++n) {
    int j = k0 + n*16 + l15;
    float s = 0.f;
    #pragma unroll
    for (int m = 0; m < 4; ++m) {
      #pragma unroll
      for (int r = 0; r < 4; ++r) {
        int e = w*64 + m*16 + g*4 + r;
        float gv = acc[m][n][r] + u_s[e] + Vm[e*512 + j];
        s += aw2_s[e] * fmaxf(gv, 0.f);
      }
    }
    s += __shfl_xor(s, 16);
    s += __shfl_xor(s, 32);
    part[n] = s;
  }
  if (l < 16) {
    #pragma unroll
    for (int n = 0; n < 4; ++n) red[w][n*16 + l] = part[n];
  }
  __syncthreads();
  if (t < 64) {
    float s = red[0][t] + red[1][t] + red[2][t] + red[3][t] + ab2[0];
    outScores[p0 + t] = s;
    float mn = s;
    #pragma unroll
    for (int off = 32; off; off >>= 1) mn = fminf(mn, __shfl_xor(mn, off));
    if (t == 0) atomicMin(wsMin, encf(mn));
  }
}

// ---------------- KS: mask + softmax -> masked scores (out) + prob bf16 ----------------
__global__ __launch_bounds__(256) void ksoftmax(
    const void* __restrict__ maskp,
    const unsigned* __restrict__ wsMin, const unsigned* __restrict__ wsFlag,
    float* __restrict__ scores, unsigned short* __restrict__ prob) {
  __shared__ float srow[512];
  __shared__ float redl[8];
  const int t = threadIdx.x, w = t >> 6, l = t & 63;
  const int q = blockIdx.x;
  const float neg = decf(*wsMin) - 20.0f;
  const unsigned flag = *wsFlag;

  for (int k = t; k < 512; k += 256) {
    float raw = scores[q*512 + k];
    bool mv;
    if (flag == 1)      mv = ((const int*)maskp)[q*512 + k] != 0;
    else if (flag == 2) mv = ((const float*)maskp)[q*512 + k] != 0.f;
    else                mv = ((const unsigned char*)maskp)[q*512 + k] != 0;
    float ms = raw + (mv ? 0.f : neg);
    scores[q*512 + k] = ms;
    srow[k] = ms;
  }
  __syncthreads();
  float lm = fmaxf(srow[t], srow[t + 256]);
  #pragma unroll
  for (int off = 32; off; off >>= 1) lm = fmaxf(lm, __shfl_xor(lm, off));
  if (l == 0) redl[w] = lm;
  __syncthreads();
  float rmax = fmaxf(fmaxf(redl[0], redl[1]), fmaxf(redl[2], redl[3]));
  float e0 = __expf(srow[t] - rmax), e1 = __expf(srow[t + 256] - rmax);
  float ls = e0 + e1;
  #pragma unroll
  for (int off = 32; off; off >>= 1) ls += __shfl_xor(ls, off);
  if (l == 0) redl[4 + w] = ls;
  __syncthreads();
  float inv = 1.0f / (redl[4] + redl[5] + redl[6] + redl[7]);
  prob[q*512 + t]       = f2bf(e0 * inv);
  prob[q*512 + t + 256] = f2bf(e1 * inv);
}

extern "C" void kernel_launch(void* const* d_in, const int* in_sizes, int n_in,
                              void* d_out, int out_size, void* d_ws, size_t ws_size,
                              hipStream_t stream) {
  const float* x      = (const float*)d_in[0];
  const float* source = (const float*)d_in[1];
  const float* dist   = (const float*)d_in[2];
  const void*  mask   = (const void*)d_in[3];
  const float* aW1    = (const float*)d_in[4];
  const float* ab1    = (const float*)d_in[5];
  const float* aW2    = (const float*)d_in[6];
  const float* ab2    = (const float*)d_in[7];
  const float* mW1    = (const float*)d_in[8];
  const float* mb1    = (const float*)d_in[9];
  const float* mW2    = (const float*)d_in[10];
  const float* mb2    = (const float*)d_in[11];

  float* outMain = (float*)d_out;             // (1,256,512)
  float* scores  = outMain + 256*512;         // (1,512,512)

  char* ws = (char*)d_ws;
  unsigned* wsMin  = (unsigned*)ws;
  unsigned* wsFlag = wsMin + 1;
  unsigned short* Cb    = (unsigned short*)(ws + 1024);     // 256x256 bf16
  float*          Up    = (float*)(ws + 132096);            // 512x256 f32
  float*          Vm    = (float*)(ws + 656384);            // 256x512 f32
  unsigned short* srcbf = (unsigned short*)(ws + 1180672);  // 256x512 bf16 [d][k]
  unsigned short* srcT  = (unsigned short*)(ws + 1442816);  // 512x256 bf16 [k][c]
  unsigned short* mW1b  = (unsigned short*)(ws + 1704960);  // 512x512 bf16
  unsigned short* mW2b  = (unsigned short*)(ws + 2229248);  // 256x512 bf16
  unsigned short* aW1A  = (unsigned short*)(ws + 2491392);  // 256x256 bf16
  unsigned short* aW1B  = (unsigned short*)(ws + 2622464);  // 256x256 bf16
  unsigned short* catT  = (unsigned short*)(ws + 2753536);  // 512x512 bf16 [q][c]
  unsigned short* prob  = (unsigned short*)(ws + 3277824);  // 512x512 bf16 [q][k]
  unsigned short* h2T   = (unsigned short*)(ws + 3802112);  // 512x512 bf16 [q][o]

  hipLaunchKernelGGL(kinit, dim3(1), dim3(64), 0, stream,
                     (const unsigned*)mask, wsMin, wsFlag);
  hipLaunchKernelGGL(kconvert, dim3(1728), dim3(256), 0, stream,
                     aW1, source, x, mW1, mW2, Cb, srcbf, srcT, mW1b, mW2b, aW1A, aW1B, catT);
  // U'[q][e] = xT @ aW1A + ab1
  hipLaunchKernelGGL((gemm_k<4, 8>),  dim3(32), dim3(256), 0, stream,
                     catT, 512, aW1A, 256, ab1, (void*)Up, 256, 4);
  // V[e][k] = aW1B @ source
  hipLaunchKernelGGL((gemm_k<0, 8>),  dim3(32), dim3(256), 0, stream,
                     aW1B, 256, srcT, 256, (const float*)nullptr, (void*)Vm, 512, 8);
  hipLaunchKernelGGL(kscores, dim3(4096), dim3(256), 0, stream,
                     dist, Cb, Up, Vm, aW2, ab2, scores, wsMin);
  hipLaunchKernelGGL(ksoftmax, dim3(512), dim3(256), 0, stream,
                     mask, wsMin, wsFlag, scores, prob);
  // msgT[q][d] = prob @ source^T  -> catT[:, 256:]
  hipLaunchKernelGGL((gemm_k<1, 16>), dim3(32), dim3(256), 0, stream,
                     prob, 512, srcbf, 512, (const float*)nullptr, (void*)(catT + 256), 512, 4);
  // h2T[q][o] = relu(catT @ mW1^T + mb1)
  hipLaunchKernelGGL((gemm_k<7, 16>), dim3(64), dim3(256), 0, stream,
                     catT, 512, mW1b, 512, mb1, (void*)h2T, 512, 8);
  // out[o2][q] = mW2 @ h2 + mb2
  hipLaunchKernelGGL((gemm_k<8, 16>), dim3(32), dim3(256), 0, stream,
                     mW2b, 512, h2T, 512, mb2, (void*)outMain, 512, 8);
}